// Round 13
// baseline (31.895 us; speedup 1.0000x reference)
//
#include <hip/hip_runtime.h>
#include <stdint.h>

// Multi-label NMS, N=8192, 80 classes.
// Per-class greedy NMS == global greedy NMS with same-label coupling.
//
// Round-13 = round-12 + K1 at c=4 done right (round-11's c=4 idea, but with
// 256-thread blocks so all 4 SIMDs/CU stay occupied):
//   K1: BI=1024 i's/block, SEG=256 j's staged in LDS, 4 i's per thread ->
//       one LDS key-read serves 4 compares; 256 blocks (1/CU).
//   K2: identical to round 12 except partial-sum runs over 32 segments.

#define NUM_CLASSES 80
#define MROW 256     // bitmask capacity per class (m ~ 102 +- 10, max ~140)
#define SEG  256     // j-segment per rank block
#define BI   1024    // i's per rank block

typedef unsigned long long u64;
typedef unsigned int u32;
typedef unsigned short u16;

__device__ __forceinline__ u32 mono_key(float s) {
    u32 u = __float_as_uint(s);
    return (u & 0x80000000u) ? ~u : (u | 0x80000000u);
}
// key = mono(score)(32b) | ~j(32b): descending score, ties by ascending index
// (matches stable argsort(-scores)). Real keys always > 0 padding.
__device__ __forceinline__ u64 make_key(float s, int j) {
    return ((u64)mono_key(s) << 32) | (u32)(~j);
}
__device__ __forceinline__ u64 rdlane64(u64 v, int l) {
    u32 lo = (u32)__builtin_amdgcn_readlane((int)(u32)v, l);
    u32 hi = (u32)__builtin_amdgcn_readlane((int)(u32)(v >> 32), l);
    return ((u64)hi << 32) | lo;
}

// ---- K1: global-rank partials, 4 i's per thread, 256-thread blocks ----------
__global__ void __launch_bounds__(256)
rank_kernel(const float* __restrict__ scores, u16* __restrict__ rank16,
            int* __restrict__ done, int N) {
    __shared__ u64 ks[SEG];
    const int t = threadIdx.x;
    if (blockIdx.x == 0 && blockIdx.y == 0 && t == 0) *done = 0; // re-arm cap
    {
        int j = blockIdx.y * SEG + t;      // t in [0,256) == SEG
        ks[t] = (j < N) ? make_key(scores[j], j) : 0ULL;
    }
    __syncthreads();
    const int i0 = blockIdx.x * BI + t;    // 4 coalesced groups of 256
    const int i1 = i0 + 256, i2 = i0 + 512, i3 = i0 + 768;
    const u64 k0 = (i0 < N) ? make_key(scores[i0], i0) : ~0ULL;
    const u64 k1 = (i1 < N) ? make_key(scores[i1], i1) : ~0ULL;
    const u64 k2 = (i2 < N) ? make_key(scores[i2], i2) : ~0ULL;
    const u64 k3 = (i3 < N) ? make_key(scores[i3], i3) : ~0ULL;
    int c0 = 0, c1 = 0, c2 = 0, c3 = 0;
    #pragma unroll 8
    for (int q = 0; q < SEG; ++q) {
        u64 k = ks[q];                     // one LDS read serves 4 compares
        c0 += (k > k0) ? 1 : 0;
        c1 += (k > k1) ? 1 : 0;
        c2 += (k > k2) ? 1 : 0;
        c3 += (k > k3) ? 1 : 0;
    }
    // per-segment counts <= 256; 32-segment sums <= 8191 -> u16 safe
    u16* rp = rank16 + (size_t)blockIdx.y * N;
    if (i0 < N) rp[i0] = (u16)c0;
    if (i1 < N) rp[i1] = (u16)c1;
    if (i2 < N) rp[i2] = (u16)c2;
    if (i3 < N) rp[i3] = (u16)c3;
}

// ---- K2: per-class gather (3 latency stages) + bitmask NMS + outputs --------
__global__ void __launch_bounds__(512)
nms2_kernel(const float* __restrict__ boxes, const int* __restrict__ labels,
            const u16* __restrict__ rank16, const float* __restrict__ thresh_p,
            const int* __restrict__ mp_ptr, int* __restrict__ done,
            float* __restrict__ out_boxes, float* __restrict__ out_order,
            float* __restrict__ out_keep, int N, int nseg) {
    const int c    = blockIdx.x;
    const int t    = threadIdx.x;          // 512 threads = 8 waves
    const int lane = t & 63;
    const int w    = t >> 6;
    const float th = *thresh_p;
    const int   mp = *mp_ptr;
    const float4* b4 = (const float4*)boxes;

    __shared__ float4 lbox[MROW];          // 4 KB
    __shared__ int    rrs[MROW];           // 1 KB
    __shared__ u64    R[MROW][4];          // 8 KB suppression rows
    __shared__ int    ilist[MROW];         // 1 KB own-class original indices
    __shared__ u32    rs[MROW];            // 1 KB global ranks
    __shared__ u64    aliveS[4];
    __shared__ int    m_s;

    // ---- init + upfront label loads (all 4 int4 issued before any use) -----
    const int4* lab4 = (const int4*)labels;
    const int nv = N >> 2;                 // int4 count
    int4 L0 = (t           < nv) ? lab4[t]            : make_int4(-1,-1,-1,-1);
    int4 L1 = (512 + t     < nv) ? lab4[512 + t]      : make_int4(-1,-1,-1,-1);
    int4 L2 = (1024 + t    < nv) ? lab4[1024 + t]     : make_int4(-1,-1,-1,-1);
    int4 L3 = (1536 + t    < nv) ? lab4[1536 + t]     : make_int4(-1,-1,-1,-1);
    if (t == 0) m_s = 0;
    ((u64*)R)[t]       = 0ULL;             // zero all 1024 row-words
    ((u64*)R)[t + 512] = 0ULL;
    __syncthreads();

    // ---- scan: hits -> ilist (order arbitrary; cr sort fixes it) -----------
    #pragma unroll
    for (int p = 0; p < 4; ++p) {
        int4 lv = (p == 0) ? L0 : (p == 1) ? L1 : (p == 2) ? L2 : L3;
        int ib = p * 2048 + 4 * t;
        #pragma unroll
        for (int k = 0; k < 4; ++k) {
            int lab = (k == 0) ? lv.x : (k == 1) ? lv.y : (k == 2) ? lv.z : lv.w;
            if (lab == c) {
                int pos = atomicAdd(&m_s, 1);
                int i = ib + k;
                if (pos < MROW) {
                    ilist[pos] = i;
                } else {
                    // overflow insurance (unreachable at m ~ 140): serial sum,
                    // emit as kept.
                    u32 s = 0;
                    for (int g = 0; g < nseg; ++g) s += rank16[g * N + i];
                    ((float4*)out_boxes)[s] = b4[i];
                    out_keep[s]  = 1.0f;
                    out_order[s] = (float)i;
                }
            }
        }
    }
    __syncthreads();
    const int mtot = m_s;
    const int me   = (mtot < MROW) ? mtot : MROW;

    if (me > 0) {
        // ---- per-entry rank sum: nseg independent loads (ILP), box load
        // issued early so its latency overlaps the next stage.
        int    ei  = 0;
        float4 bbx = make_float4(0.f, 0.f, 0.f, 0.f);
        if (t < me) {
            ei  = ilist[t];
            bbx = b4[ei];                  // issue early; consumed after sync
            u32 s = 0;
            #pragma unroll 8
            for (int g = 0; g < nseg; ++g) s += (u32)rank16[g * N + ei];
            rs[t] = s;
        }
        __syncthreads();

        // ---- cr by counting sort over ranks (distinct), slots + out_order --
        if (t < me) {
            u32 r = rs[t];
            int cr = 0;
            for (int e2 = 0; e2 < me; ++e2) cr += (rs[e2] < r) ? 1 : 0;
            out_order[r] = (float)ei;
            lbox[cr] = bbx;
            rrs[cr]  = (int)r;
        }
        __syncthreads();

        // ---- phase A: suppression rows via ballot; 8 waves split each
        // word's suppressor range [0, lim).
        for (int sw = 0; sw * 64 < me; ++sw) {
            const int myslot = sw * 64 + lane;
            float4 mb = make_float4(0.f, 0.f, 0.f, 0.f);
            float mar = 0.f;
            if (myslot < me) { mb = lbox[myslot]; mar = (mb.z - mb.x) * (mb.w - mb.y); }
            int lim = (sw + 1) * 64; if (lim > me) lim = me;   // i < lim can suppress
            int chunk = (lim + 7) >> 3;
            int lo = w * chunk;
            int hi = lo + chunk; if (hi > lim) hi = lim;
            for (int i = lo; i < hi; ++i) {
                float4 bi = lbox[i];                           // uniform broadcast
                float ai = (bi.z - bi.x) * (bi.w - bi.y);
                float lx = fmaxf(bi.x, mb.x), ly = fmaxf(bi.y, mb.y);
                float rx = fminf(bi.z, mb.z), ry = fminf(bi.w, mb.w);
                float ww = fmaxf(rx - lx, 0.f), hh = fmaxf(ry - ly, 0.f);
                float inter = ww * hh;
                float iou = inter / (ai + mar - inter);        // exact, matches ref
                u64 mask = __ballot(iou > th && myslot > i);
                if (lane == 0 && mask) R[i][sw] = mask;        // rows pre-zeroed
            }
        }
        __syncthreads();

        // ---- phase B: wave 0 finalizes words in order; nz ballots skip
        // empty rows; <= 9 u64 rows live at once (word-scoped, no spills).
        if (w == 0) {
            u64 a0 = 0, a1 = 0, a2 = 0, a3 = 0;
            {   // word 0
                u64 rw0 = R[lane][0];
                u64 nz0 = __ballot(rw0 != 0ULL);
                int n = me > 64 ? 64 : me;
                u64 a = (n >= 64) ? ~0ULL : ((1ULL << n) - 1ULL);
                for (int bb = 0; bb < n; ++bb)
                    if (((a & nz0) >> bb) & 1ULL) a &= ~rdlane64(rw0, bb);
                a0 = a;
            }
            if (me > 64) {   // word 1
                u64 rw0 = R[lane][1], rw1 = R[64 + lane][1];
                u64 nz0 = __ballot(rw0 != 0ULL), nz1 = __ballot(rw1 != 0ULL);
                int n = (me - 64) > 64 ? 64 : (me - 64);
                u64 a = (n >= 64) ? ~0ULL : ((1ULL << n) - 1ULL);
                for (int bb = 0; bb < 64; ++bb)
                    if (((a0 & nz0) >> bb) & 1ULL) a &= ~rdlane64(rw0, bb);
                for (int bb = 0; bb < n; ++bb)
                    if (((a & nz1) >> bb) & 1ULL) a &= ~rdlane64(rw1, bb);
                a1 = a;
            }
            if (me > 128) {  // word 2
                u64 rw0 = R[lane][2], rw1 = R[64 + lane][2], rw2 = R[128 + lane][2];
                u64 nz0 = __ballot(rw0 != 0ULL), nz1 = __ballot(rw1 != 0ULL),
                    nz2 = __ballot(rw2 != 0ULL);
                int n = (me - 128) > 64 ? 64 : (me - 128);
                u64 a = (n >= 64) ? ~0ULL : ((1ULL << n) - 1ULL);
                for (int bb = 0; bb < 64; ++bb)
                    if (((a0 & nz0) >> bb) & 1ULL) a &= ~rdlane64(rw0, bb);
                for (int bb = 0; bb < 64; ++bb)
                    if (((a1 & nz1) >> bb) & 1ULL) a &= ~rdlane64(rw1, bb);
                for (int bb = 0; bb < n; ++bb)
                    if (((a & nz2) >> bb) & 1ULL) a &= ~rdlane64(rw2, bb);
                a2 = a;
            }
            if (me > 192) {  // word 3
                u64 rw0 = R[lane][3], rw1 = R[64 + lane][3],
                    rw2 = R[128 + lane][3], rw3 = R[192 + lane][3];
                u64 nz0 = __ballot(rw0 != 0ULL), nz1 = __ballot(rw1 != 0ULL),
                    nz2 = __ballot(rw2 != 0ULL), nz3 = __ballot(rw3 != 0ULL);
                int n = me - 192;
                u64 a = (n >= 64) ? ~0ULL : ((1ULL << n) - 1ULL);
                for (int bb = 0; bb < 64; ++bb)
                    if (((a0 & nz0) >> bb) & 1ULL) a &= ~rdlane64(rw0, bb);
                for (int bb = 0; bb < 64; ++bb)
                    if (((a1 & nz1) >> bb) & 1ULL) a &= ~rdlane64(rw1, bb);
                for (int bb = 0; bb < 64; ++bb)
                    if (((a2 & nz2) >> bb) & 1ULL) a &= ~rdlane64(rw2, bb);
                for (int bb = 0; bb < n; ++bb)
                    if (((a & nz3) >> bb) & 1ULL) a &= ~rdlane64(rw3, bb);
                a3 = a;
            }
            if (lane < 4)
                aliveS[lane] = (lane == 0) ? a0 : (lane == 1) ? a1
                             : (lane == 2) ? a2 : a3;
        }
        __syncthreads();

        // ---- outputs for slots 0..me-1
        if (t < me) {
            int kept = (int)((aliveS[t >> 6] >> (t & 63)) & 1ULL);
            int r = rrs[t];
            float4 bb2 = lbox[t];
            float4 z = make_float4(0.f, 0.f, 0.f, 0.f);
            ((float4*)out_boxes)[r] = kept ? bb2 : z;
            out_keep[r] = kept ? 1.0f : 0.0f;
        }
    }

    // ---- fused max_proposals cap: tail-block pattern, no-op when mp<=0 ------
    if (mp > 0) {
        __syncthreads();
        __threadfence();
        if (t == 0) {
            int old = atomicAdd(done, 1);
            if (old == NUM_CLASSES - 1) {
                __threadfence();
                int cnt = 0;
                for (int j = 0; j < N; ++j) {
                    if (out_keep[j] > 0.0f) {
                        if (++cnt > mp) {
                            out_keep[j] = 0.0f;
                            ((float4*)out_boxes)[j] = make_float4(0.f, 0.f, 0.f, 0.f);
                        }
                    }
                }
            }
        }
    }
}

extern "C" void kernel_launch(void* const* d_in, const int* in_sizes, int n_in,
                              void* d_out, int out_size, void* d_ws, size_t ws_size,
                              hipStream_t stream) {
    const int N = in_sizes[0] / 4;
    const float* boxes  = (const float*)d_in[0];
    const float* scores = (const float*)d_in[1];
    const int*   labels = (const int*)d_in[2];
    const float* thresh = (const float*)d_in[3];
    const int*   maxp   = (const int*)d_in[4];

    float* out       = (float*)d_out;
    float* out_boxes = out;                    // N*4
    float* out_order = out + 4 * (size_t)N;    // N
    float* out_keep  = out + 5 * (size_t)N;    // N

    const int nseg = (N + SEG - 1) / SEG;      // 32

    // workspace: done (64B) | rank16 (nseg*N u16 = 512KB)
    char* w = (char*)d_ws;
    int* done   = (int*)w;
    u16* rank16 = (u16*)(w + 64);

    const int gx = (N + BI - 1) / BI;          // 8

    rank_kernel<<<dim3(gx, nseg), 256, 0, stream>>>(scores, rank16, done, N);
    nms2_kernel<<<NUM_CLASSES, 512, 0, stream>>>(boxes, labels, rank16, thresh,
                                                 maxp, done,
                                                 out_boxes, out_order, out_keep,
                                                 N, nseg);
}

// Round 14
// 30.149 us; speedup vs baseline: 1.0579x; 1.0579x over previous
//
#include <hip/hip_runtime.h>
#include <stdint.h>

// Multi-label NMS, N=8192, 80 classes.
// Per-class greedy NMS == global greedy NMS with same-label coupling.
//
// FINAL (= round-12, best measured 30.2us): 2 kernels.
//   K1 rank: N^2 counting sort partials (u64 keys: mono-score | ~index for
//            exact stable argsort(-scores) tie-break), 2 i's per thread,
//            16 j-segments staged in LDS. 67M u64 compares, VALU-lean.
//   K2 nms2: per-class block: label scan (upfront int4 loads) -> per-entry
//            16-way ILP partial sum (box load issued early, latency hidden
//            under the cr counting sort) -> phase A suppression-bitmask rows
//            via ballot (8 waves split each word's suppressor range) ->
//            phase B word-scoped greedy walk (wave 0, <= 9 u64 live, nz
//            ballots skip empty rows; no register spills) -> outputs.
// max_proposals==0 in this dataset; mp>0 handled by fused tail-block cap.
//
// Session findings baked in: multi-phase single-kernel fusion spills to
// scratch (r5/r7: VGPR 16/24 + ~900KB phantom WRITE); serial global-load
// chains at idle clocks cost ~350ns each (r8); workload is latency-floor
// bound at ~30us (r11-13: +-50% instruction perturbations move <5%).

#define NUM_CLASSES 80
#define MROW 256     // bitmask capacity per class (m ~ 102 +- 10, max ~140)

typedef unsigned long long u64;
typedef unsigned int u32;
typedef unsigned short u16;

__device__ __forceinline__ u32 mono_key(float s) {
    u32 u = __float_as_uint(s);
    return (u & 0x80000000u) ? ~u : (u | 0x80000000u);
}
// key = mono(score)(32b) | ~j(32b): descending score, ties by ascending index
// (matches stable argsort(-scores)). Real keys always > 0 padding.
__device__ __forceinline__ u64 make_key(float s, int j) {
    return ((u64)mono_key(s) << 32) | (u32)(~j);
}
__device__ __forceinline__ u64 rdlane64(u64 v, int l) {
    u32 lo = (u32)__builtin_amdgcn_readlane((int)(u32)v, l);
    u32 hi = (u32)__builtin_amdgcn_readlane((int)(u32)(v >> 32), l);
    return ((u64)hi << 32) | lo;
}

// ---- K1: global-rank partials, 2 i's per thread -----------------------------
__global__ void __launch_bounds__(256)
rank_kernel(const float* __restrict__ scores, u16* __restrict__ rank16,
            int* __restrict__ done, int N) {
    __shared__ u64 ks[512];
    const int t = threadIdx.x;
    if (blockIdx.x == 0 && blockIdx.y == 0 && t == 0) *done = 0; // re-arm cap
    const int j0 = blockIdx.y * 512;
    for (int q = t; q < 512; q += 256) {
        int j = j0 + q;
        ks[q] = (j < N) ? make_key(scores[j], j) : 0ULL;
    }
    __syncthreads();
    const int i0 = blockIdx.x * 512 + t;
    const int i1 = i0 + 256;
    const u64 k0 = (i0 < N) ? make_key(scores[i0], i0) : ~0ULL;
    const u64 k1 = (i1 < N) ? make_key(scores[i1], i1) : ~0ULL;
    int c0 = 0, c1 = 0;
    #pragma unroll 16
    for (int q = 0; q < 512; ++q) {
        u64 k = ks[q];                     // one LDS read serves both i's
        c0 += (k > k0) ? 1 : 0;
        c1 += (k > k1) ? 1 : 0;
    }
    // per-segment counts <= 512 -> u16; 16-segment sums <= 8191 -> u16 safe
    if (i0 < N) rank16[blockIdx.y * N + i0] = (u16)c0;
    if (i1 < N) rank16[blockIdx.y * N + i1] = (u16)c1;
}

// ---- K2: per-class gather (3 latency stages) + bitmask NMS + outputs --------
__global__ void __launch_bounds__(512)
nms2_kernel(const float* __restrict__ boxes, const int* __restrict__ labels,
            const u16* __restrict__ rank16, const float* __restrict__ thresh_p,
            const int* __restrict__ mp_ptr, int* __restrict__ done,
            float* __restrict__ out_boxes, float* __restrict__ out_order,
            float* __restrict__ out_keep, int N, int nseg) {
    const int c    = blockIdx.x;
    const int t    = threadIdx.x;          // 512 threads = 8 waves
    const int lane = t & 63;
    const int w    = t >> 6;
    const float th = *thresh_p;
    const int   mp = *mp_ptr;
    const float4* b4 = (const float4*)boxes;

    __shared__ float4 lbox[MROW];          // 4 KB
    __shared__ int    rrs[MROW];           // 1 KB
    __shared__ u64    R[MROW][4];          // 8 KB suppression rows
    __shared__ int    ilist[MROW];         // 1 KB own-class original indices
    __shared__ u32    rs[MROW];            // 1 KB global ranks
    __shared__ u64    aliveS[4];
    __shared__ int    m_s;

    // ---- init + upfront label loads (all 4 int4 issued before any use) -----
    const int4* lab4 = (const int4*)labels;
    const int nv = N >> 2;                 // int4 count
    int4 L0 = (t           < nv) ? lab4[t]            : make_int4(-1,-1,-1,-1);
    int4 L1 = (512 + t     < nv) ? lab4[512 + t]      : make_int4(-1,-1,-1,-1);
    int4 L2 = (1024 + t    < nv) ? lab4[1024 + t]     : make_int4(-1,-1,-1,-1);
    int4 L3 = (1536 + t    < nv) ? lab4[1536 + t]     : make_int4(-1,-1,-1,-1);
    if (t == 0) m_s = 0;
    ((u64*)R)[t]       = 0ULL;             // zero all 1024 row-words
    ((u64*)R)[t + 512] = 0ULL;
    __syncthreads();

    // ---- scan: hits -> ilist (order arbitrary; cr sort fixes it) -----------
    #pragma unroll
    for (int p = 0; p < 4; ++p) {
        int4 lv = (p == 0) ? L0 : (p == 1) ? L1 : (p == 2) ? L2 : L3;
        int ib = p * 2048 + 4 * t;
        #pragma unroll
        for (int k = 0; k < 4; ++k) {
            int lab = (k == 0) ? lv.x : (k == 1) ? lv.y : (k == 2) ? lv.z : lv.w;
            if (lab == c) {
                int pos = atomicAdd(&m_s, 1);
                int i = ib + k;
                if (pos < MROW) {
                    ilist[pos] = i;
                } else {
                    // overflow insurance (unreachable at m ~ 140): serial sum,
                    // emit as kept.
                    u32 s = 0;
                    for (int g = 0; g < nseg; ++g) s += rank16[g * N + i];
                    ((float4*)out_boxes)[s] = b4[i];
                    out_keep[s]  = 1.0f;
                    out_order[s] = (float)i;
                }
            }
        }
    }
    __syncthreads();
    const int mtot = m_s;
    const int me   = (mtot < MROW) ? mtot : MROW;

    if (me > 0) {
        // ---- per-entry rank sum: 16 independent loads (ILP), box load
        // issued here too so its latency overlaps the next stage.
        int    ei  = 0;
        float4 bbx = make_float4(0.f, 0.f, 0.f, 0.f);
        if (t < me) {
            ei  = ilist[t];
            bbx = b4[ei];                  // issue early; consumed after sync
            u32 s = 0;
            #pragma unroll
            for (int g = 0; g < 16; ++g) s += (u32)rank16[g * N + ei];
            rs[t] = s;
        }
        __syncthreads();

        // ---- cr by counting sort over ranks (distinct), slots + out_order --
        if (t < me) {
            u32 r = rs[t];
            int cr = 0;
            for (int e2 = 0; e2 < me; ++e2) cr += (rs[e2] < r) ? 1 : 0;
            out_order[r] = (float)ei;
            lbox[cr] = bbx;
            rrs[cr]  = (int)r;
        }
        __syncthreads();

        // ---- phase A: suppression rows via ballot; 8 waves split each
        // word's suppressor range [0, lim).
        for (int sw = 0; sw * 64 < me; ++sw) {
            const int myslot = sw * 64 + lane;
            float4 mb = make_float4(0.f, 0.f, 0.f, 0.f);
            float mar = 0.f;
            if (myslot < me) { mb = lbox[myslot]; mar = (mb.z - mb.x) * (mb.w - mb.y); }
            int lim = (sw + 1) * 64; if (lim > me) lim = me;   // i < lim can suppress
            int chunk = (lim + 7) >> 3;
            int lo = w * chunk;
            int hi = lo + chunk; if (hi > lim) hi = lim;
            for (int i = lo; i < hi; ++i) {
                float4 bi = lbox[i];                           // uniform broadcast
                float ai = (bi.z - bi.x) * (bi.w - bi.y);
                float lx = fmaxf(bi.x, mb.x), ly = fmaxf(bi.y, mb.y);
                float rx = fminf(bi.z, mb.z), ry = fminf(bi.w, mb.w);
                float ww = fmaxf(rx - lx, 0.f), hh = fmaxf(ry - ly, 0.f);
                float inter = ww * hh;
                float iou = inter / (ai + mar - inter);        // exact, matches ref
                u64 mask = __ballot(iou > th && myslot > i);
                if (lane == 0 && mask) R[i][sw] = mask;        // rows pre-zeroed
            }
        }
        __syncthreads();

        // ---- phase B: wave 0 finalizes words in order; nz ballots skip
        // empty rows; <= 9 u64 rows live at once (word-scoped, no spills).
        if (w == 0) {
            u64 a0 = 0, a1 = 0, a2 = 0, a3 = 0;
            {   // word 0
                u64 rw0 = R[lane][0];
                u64 nz0 = __ballot(rw0 != 0ULL);
                int n = me > 64 ? 64 : me;
                u64 a = (n >= 64) ? ~0ULL : ((1ULL << n) - 1ULL);
                for (int bb = 0; bb < n; ++bb)
                    if (((a & nz0) >> bb) & 1ULL) a &= ~rdlane64(rw0, bb);
                a0 = a;
            }
            if (me > 64) {   // word 1
                u64 rw0 = R[lane][1], rw1 = R[64 + lane][1];
                u64 nz0 = __ballot(rw0 != 0ULL), nz1 = __ballot(rw1 != 0ULL);
                int n = (me - 64) > 64 ? 64 : (me - 64);
                u64 a = (n >= 64) ? ~0ULL : ((1ULL << n) - 1ULL);
                for (int bb = 0; bb < 64; ++bb)
                    if (((a0 & nz0) >> bb) & 1ULL) a &= ~rdlane64(rw0, bb);
                for (int bb = 0; bb < n; ++bb)
                    if (((a & nz1) >> bb) & 1ULL) a &= ~rdlane64(rw1, bb);
                a1 = a;
            }
            if (me > 128) {  // word 2
                u64 rw0 = R[lane][2], rw1 = R[64 + lane][2], rw2 = R[128 + lane][2];
                u64 nz0 = __ballot(rw0 != 0ULL), nz1 = __ballot(rw1 != 0ULL),
                    nz2 = __ballot(rw2 != 0ULL);
                int n = (me - 128) > 64 ? 64 : (me - 128);
                u64 a = (n >= 64) ? ~0ULL : ((1ULL << n) - 1ULL);
                for (int bb = 0; bb < 64; ++bb)
                    if (((a0 & nz0) >> bb) & 1ULL) a &= ~rdlane64(rw0, bb);
                for (int bb = 0; bb < 64; ++bb)
                    if (((a1 & nz1) >> bb) & 1ULL) a &= ~rdlane64(rw1, bb);
                for (int bb = 0; bb < n; ++bb)
                    if (((a & nz2) >> bb) & 1ULL) a &= ~rdlane64(rw2, bb);
                a2 = a;
            }
            if (me > 192) {  // word 3
                u64 rw0 = R[lane][3], rw1 = R[64 + lane][3],
                    rw2 = R[128 + lane][3], rw3 = R[192 + lane][3];
                u64 nz0 = __ballot(rw0 != 0ULL), nz1 = __ballot(rw1 != 0ULL),
                    nz2 = __ballot(rw2 != 0ULL), nz3 = __ballot(rw3 != 0ULL);
                int n = me - 192;
                u64 a = (n >= 64) ? ~0ULL : ((1ULL << n) - 1ULL);
                for (int bb = 0; bb < 64; ++bb)
                    if (((a0 & nz0) >> bb) & 1ULL) a &= ~rdlane64(rw0, bb);
                for (int bb = 0; bb < 64; ++bb)
                    if (((a1 & nz1) >> bb) & 1ULL) a &= ~rdlane64(rw1, bb);
                for (int bb = 0; bb < 64; ++bb)
                    if (((a2 & nz2) >> bb) & 1ULL) a &= ~rdlane64(rw2, bb);
                for (int bb = 0; bb < n; ++bb)
                    if (((a & nz3) >> bb) & 1ULL) a &= ~rdlane64(rw3, bb);
                a3 = a;
            }
            if (lane < 4)
                aliveS[lane] = (lane == 0) ? a0 : (lane == 1) ? a1
                             : (lane == 2) ? a2 : a3;
        }
        __syncthreads();

        // ---- outputs for slots 0..me-1
        if (t < me) {
            int kept = (int)((aliveS[t >> 6] >> (t & 63)) & 1ULL);
            int r = rrs[t];
            float4 bb2 = lbox[t];
            float4 z = make_float4(0.f, 0.f, 0.f, 0.f);
            ((float4*)out_boxes)[r] = kept ? bb2 : z;
            out_keep[r] = kept ? 1.0f : 0.0f;
        }
    }

    // ---- fused max_proposals cap: tail-block pattern, no-op when mp<=0 ------
    if (mp > 0) {
        __syncthreads();
        __threadfence();
        if (t == 0) {
            int old = atomicAdd(done, 1);
            if (old == NUM_CLASSES - 1) {
                __threadfence();
                int cnt = 0;
                for (int j = 0; j < N; ++j) {
                    if (out_keep[j] > 0.0f) {
                        if (++cnt > mp) {
                            out_keep[j] = 0.0f;
                            ((float4*)out_boxes)[j] = make_float4(0.f, 0.f, 0.f, 0.f);
                        }
                    }
                }
            }
        }
    }
}

extern "C" void kernel_launch(void* const* d_in, const int* in_sizes, int n_in,
                              void* d_out, int out_size, void* d_ws, size_t ws_size,
                              hipStream_t stream) {
    const int N = in_sizes[0] / 4;
    const float* boxes  = (const float*)d_in[0];
    const float* scores = (const float*)d_in[1];
    const int*   labels = (const int*)d_in[2];
    const float* thresh = (const float*)d_in[3];
    const int*   maxp   = (const int*)d_in[4];

    float* out       = (float*)d_out;
    float* out_boxes = out;                    // N*4
    float* out_order = out + 4 * (size_t)N;    // N
    float* out_keep  = out + 5 * (size_t)N;    // N

    const int nseg = (N + 511) / 512;          // 16

    // workspace: done (64B) | rank16 (nseg*N u16 = 256KB)
    char* w = (char*)d_ws;
    int* done   = (int*)w;
    u16* rank16 = (u16*)(w + 64);

    const int gx = (N + 511) / 512;            // 16

    rank_kernel<<<dim3(gx, nseg), 256, 0, stream>>>(scores, rank16, done, N);
    nms2_kernel<<<NUM_CLASSES, 512, 0, stream>>>(boxes, labels, rank16, thresh,
                                                 maxp, done,
                                                 out_boxes, out_order, out_keep,
                                                 N, nseg);
}